// Round 3
// baseline (8583.245 us; speedup 1.0000x reference)
//
#include <hip/hip_runtime.h>
#include <stdint.h>

typedef __attribute__((ext_vector_type(8))) short short8;
typedef __attribute__((ext_vector_type(4))) float f32x4;
typedef unsigned short u16;
typedef unsigned int u32;
typedef unsigned long long u64;

__device__ __forceinline__ float bf2f(u16 v) {
    u32 t = ((u32)v) << 16; float f; __builtin_memcpy(&f, &t, 4); return f;
}
__device__ __forceinline__ u16 f2bf(float f) {
    u32 t; __builtin_memcpy(&t, &f, 4);
    return (u16)((t + 0x7FFFu + ((t >> 16) & 1u)) >> 16);
}

// ---------------- cast x (f32 -> bf16), 4 elems/thread ----------------
__global__ __launch_bounds__(256) void cast_f32_bf16(const float* __restrict__ in,
                                                     u16* __restrict__ out, int n4) {
    int i = blockIdx.x * 256 + threadIdx.x;
    if (i < n4) {
        float4 v = ((const float4*)in)[i];
        uint2 pk;
        pk.x = (u32)f2bf(v.x) | ((u32)f2bf(v.y) << 16);
        pk.y = (u32)f2bf(v.z) | ((u32)f2bf(v.w) << 16);
        ((uint2*)out)[i] = pk;
    }
}

// ---------- transpose + cast: in f32 [K][2048] -> out bf16 [2048][K] ----------
__global__ void transpose_cast(const float* __restrict__ in, u16* __restrict__ out, int K) {
    __shared__ float tile[32][33];
    int n0 = blockIdx.x * 32, k0 = blockIdx.y * 32;
    int tx = threadIdx.x, ty = threadIdx.y; // block (32,8)
    for (int i = 0; i < 4; i++)
        tile[ty + i * 8][tx] = in[(size_t)(k0 + ty + i * 8) * 2048 + n0 + tx];
    __syncthreads();
    for (int i = 0; i < 4; i++)
        out[(size_t)(n0 + ty + i * 8) * K + k0 + tx] = f2bf(tile[tx][ty + i * 8]);
}

// ------- bf16 MFMA GEMM, epilogue writes xw in RECURRENCE-LANE-SWIZZLED layout -------
// Logical element (t, b, col) with col = g*512 + j (g=gate, j=0..511) stored at:
//   chunk = ((t*4 + mt)*8 + jb)*4 + w   [mt=b>>4, jb=j>>6, w=(j>>4)&3]
//   addr  = chunk*1024 + (q*16 + n)*16 + g*4 + r   [q=(b>>2)&3, r=b&3, n=j&15]
// so recurrence lane (w, q, n) reads its 16 u16 (4 gates x 4 batch rows) as one
// contiguous 32B block.
__global__ __launch_bounds__(256) void gemm_bt(const u16* __restrict__ A,
                                               const u16* __restrict__ Bt,
                                               const float* __restrict__ bias,
                                               u16* __restrict__ C,
                                               int M, int N, int K) {
    __shared__ u16 As[128 * 40];
    __shared__ u16 Bs[128 * 40];
    int bm = blockIdx.y, bn = blockIdx.x;
    int tid = threadIdx.x, lane = tid & 63, wv = tid >> 6;
    int n = lane & 15, q = lane >> 4;
    int wm = wv & 1, wn = wv >> 1;
    f32x4 acc[4][4] = {};
    int rowA0 = bm * 128, rowB0 = bn * 128;
    for (int kt = 0; kt < K; kt += 32) {
        uint4 va[2], vb[2];
        #pragma unroll
        for (int s = 0; s < 2; s++) {
            int slot = tid + s * 256;
            int row = slot >> 2, ko = (slot & 3) * 8;
            va[s] = *(const uint4*)(A + (size_t)(rowA0 + row) * K + kt + ko);
            vb[s] = *(const uint4*)(Bt + (size_t)(rowB0 + row) * K + kt + ko);
        }
        __syncthreads();
        #pragma unroll
        for (int s = 0; s < 2; s++) {
            int slot = tid + s * 256;
            int row = slot >> 2, ko = (slot & 3) * 8;
            *(uint4*)(As + row * 40 + ko) = va[s];
            *(uint4*)(Bs + row * 40 + ko) = vb[s];
        }
        __syncthreads();
        short8 af[4], bfr[4];
        #pragma unroll
        for (int i = 0; i < 4; i++)
            af[i] = *(const short8*)(As + (wm * 64 + i * 16 + n) * 40 + q * 8);
        #pragma unroll
        for (int j = 0; j < 4; j++)
            bfr[j] = *(const short8*)(Bs + (wn * 64 + j * 16 + n) * 40 + q * 8);
        #pragma unroll
        for (int i = 0; i < 4; i++)
            #pragma unroll
            for (int j = 0; j < 4; j++)
                acc[i][j] = __builtin_amdgcn_mfma_f32_16x16x32_bf16(af[i], bfr[j], acc[i][j], 0, 0, 0);
    }
    #pragma unroll
    for (int j = 0; j < 4; j++) {
        int col = bn * 128 + wn * 64 + j * 16 + n;
        float bv = bias[col];
        int g = col >> 9, jcol = col & 511;
        int jb = jcol >> 6, w2 = (jcol >> 4) & 3, n2 = jcol & 15;
        #pragma unroll
        for (int i = 0; i < 4; i++) {
            int row0 = bm * 128 + wm * 64 + i * 16 + q * 4;
            #pragma unroll
            for (int r = 0; r < 4; r++) {
                int row = row0 + r;
                int b = row >> 9, t = row & 511;
                int mt = b >> 4, brow = b & 15;
                int q2 = brow >> 2, r2 = brow & 3;
                size_t addr = ((((size_t)t * 4 + mt) * 8 + jb) * 4 + w2) * 1024
                              + (q2 * 16 + n2) * 16 + g * 4 + r2;
                C[addr] = f2bf(acc[i][j][r] + bv);
            }
        }
    }
}

// ---------------- persistent LSTM recurrence, zero-LDS, 8-WG sync groups ----------------
// Per 32-WG half: WG sub: mt = sub&3 (16 batches), jb = sub>>2 (64 j-cols).
// Wave w owns j in [jb*64+w*16, +16) for ALL FOUR gates -> gate math fully in-lane.
// U^T fragments register-resident (256 VGPR/wave). h exchange via agent-scope
// atomics (L2-bypass). No __syncthreads anywhere in the loop; per-wave arrivals.
__global__ __launch_bounds__(256, 1) void lstm_rec(
    const u16* __restrict__ xw0, const u16* __restrict__ Ut0, u16* __restrict__ hbA,
    u32* __restrict__ ctrA, u16* __restrict__ h1oA, float* __restrict__ foA,
    const u16* __restrict__ xw1, const u16* __restrict__ Ut1, u16* __restrict__ hbB,
    u32* __restrict__ ctrB, u16* __restrict__ h1oB, float* __restrict__ foB,
    int nhalf) {
    int bid = blockIdx.x;
    int dir = (bid >= nhalf) ? 1 : 0;
    int sub = dir ? (bid - nhalf) : bid;
    const u16* xw = dir ? xw1 : xw0;
    const u16* Ut = dir ? Ut1 : Ut0;
    u16* hbuf = dir ? hbB : hbA;
    u32* ctr = dir ? ctrB : ctrA;
    u16* h1out = dir ? h1oB : h1oA;
    float* fout = dir ? foB : foA;
    int reverse = dir;

    int mt = sub & 3, jb = sub >> 2;
    int b0 = mt * 16;
    int tid = threadIdx.x, lane = tid & 63, w = tid >> 6;
    int n = lane & 15, q = lane >> 4;
    int jcol = jb * 64 + w * 16 + n;

    // register-resident U^T fragments: 4 gate-tiles x 16 K-steps
    short8 Breg[4][16];
    #pragma unroll
    for (int g = 0; g < 4; g++)
        #pragma unroll
        for (int s = 0; s < 16; s++)
            Breg[g][s] = *(const short8*)(Ut + (size_t)(g * 512 + jcol) * 512 + s * 32 + q * 8);

    float cst[4] = {0.f, 0.f, 0.f, 0.f};
    u16 hq[4];
    float hf[4];
    u32* ctrg = ctr + mt * 512;

    // prefetch xw chunk for t=0
    uint4 xwv0, xwv1;
    {
        int tt0 = reverse ? 511 : 0;
        const u16* p = xw + ((((size_t)tt0 * 4 + mt) * 8 + jb) * 4 + w) * 1024 + lane * 16;
        xwv0 = *(const uint4*)p;
        xwv1 = *(const uint4*)(p + 8);
    }

    for (int t = 0; t < 512; t++) {
        int par = t & 1;
        const u16* hrd = hbuf + par * (64 * 512);

        // h_{t-1} A-fragments: agent-coherent u64 loads straight into registers
        union { u64 d[2]; short8 v; } Af[16];
        #pragma unroll
        for (int s = 0; s < 16; s++) {
            const u64* p = (const u64*)(hrd + (size_t)(b0 + n) * 512 + s * 32 + q * 8);
            Af[s].d[0] = __hip_atomic_load(p, __ATOMIC_RELAXED, __HIP_MEMORY_SCOPE_AGENT);
            Af[s].d[1] = __hip_atomic_load(p + 1, __ATOMIC_RELAXED, __HIP_MEMORY_SCOPE_AGENT);
        }

        // init acc from the xw chunk prefetched last step (already drained)
        f32x4 acc[4];
        {
            const u16* xa = (const u16*)&xwv0;
            const u16* xb = (const u16*)&xwv1;
            #pragma unroll
            for (int r = 0; r < 4; r++) {
                acc[0][r] = bf2f(xa[r]);
                acc[1][r] = bf2f(xa[4 + r]);
                acc[2][r] = bf2f(xb[r]);
                acc[3][r] = bf2f(xb[4 + r]);
            }
        }

        // prefetch xw for t+1 (issued AFTER A-frag loads: in-order vmcnt retirement
        // means an older HBM miss would otherwise gate the MFMA's waitcnt)
        if (t < 511) {
            int ttn = reverse ? (511 - (t + 1)) : (t + 1);
            const u16* p = xw + ((((size_t)ttn * 4 + mt) * 8 + jb) * 4 + w) * 1024 + lane * 16;
            xwv0 = *(const uint4*)p;
            xwv1 = *(const uint4*)(p + 8);
        }

        // deferred output stores from the previous step (not ordering-critical)
        if (t > 0) {
            int tp = reverse ? (512 - t) : (t - 1);
            #pragma unroll
            for (int r = 0; r < 4; r++) {
                size_t row = (size_t)(b0 + q * 4 + r) * 512 + tp;
                if (h1out) h1out[row * 512 + jcol] = hq[r];
                if (fout) fout[row * 1024 + jcol] = hf[r];
            }
        }

        // z = xw + h @ U  (4 gate-tiles, K=512)
        #pragma unroll
        for (int s = 0; s < 16; s++)
            #pragma unroll
            for (int g = 0; g < 4; g++)
                acc[g] = __builtin_amdgcn_mfma_f32_16x16x32_bf16(Af[s].v, Breg[g][s], acc[g], 0, 0, 0);

        // gate math, fully in-lane; h store via agent-scope (write-through) atomics
        u16* hwr = hbuf + (1 - par) * (64 * 512);
        #pragma unroll
        for (int r = 0; r < 4; r++) {
            float zi = acc[0][r], zf = acc[1][r], zg = acc[2][r], zo = acc[3][r];
            float si = 1.f / (1.f + __expf(-zi));
            float sf = 1.f / (1.f + __expf(-zf));
            float so = 1.f / (1.f + __expf(-zo));
            float gg = zg > 0.f ? zg : 0.f;
            cst[r] = sf * cst[r] + si * gg;
            float h = so * (cst[r] > 0.f ? cst[r] : 0.f);
            hf[r] = h;
            hq[r] = f2bf(h);
            __hip_atomic_store(hwr + (size_t)(b0 + q * 4 + r) * 512 + jcol, hq[r],
                               __ATOMIC_RELAXED, __HIP_MEMORY_SCOPE_AGENT);
        }
        // drain h stores to the coherence point before signaling arrival
        asm volatile("s_waitcnt vmcnt(0)" ::: "memory");
        if (lane == 0) {
            __hip_atomic_fetch_add(ctrg + t, 1u, __ATOMIC_RELAXED, __HIP_MEMORY_SCOPE_AGENT);
            while (__hip_atomic_load(ctrg + t, __ATOMIC_RELAXED, __HIP_MEMORY_SCOPE_AGENT) < 32u) {}
        }
        asm volatile("" ::: "memory");
    }
    // final deferred output store (t = 511)
    {
        int tp = reverse ? 0 : 511;
        #pragma unroll
        for (int r = 0; r < 4; r++) {
            size_t row = (size_t)(b0 + q * 4 + r) * 512 + tp;
            if (h1out) h1out[row * 512 + jcol] = hq[r];
            if (fout) fout[row * 1024 + jcol] = hf[r];
        }
    }
}

// ---------------- LayerNorm(concat) + residual, in-place on d_out ----------------
__global__ __launch_bounds__(256) void ln_res(float* __restrict__ out,
                                              const float* __restrict__ x,
                                              const float* __restrict__ gamma,
                                              const float* __restrict__ beta) {
    int row = blockIdx.x;
    int tid = threadIdx.x, lane = tid & 63, wv = tid >> 6;
    const float4 hv = ((const float4*)(out + (size_t)row * 1024))[tid];
    const float4 xv = ((const float4*)(x + (size_t)row * 1024))[tid];
    float s = hv.x + hv.y + hv.z + hv.w;
    float ss = hv.x * hv.x + hv.y * hv.y + hv.z * hv.z + hv.w * hv.w;
    for (int o = 32; o > 0; o >>= 1) {
        s += __shfl_down(s, o);
        ss += __shfl_down(ss, o);
    }
    __shared__ float as_[4], bs_[4];
    if (lane == 0) { as_[wv] = s; bs_[wv] = ss; }
    __syncthreads();
    s = as_[0] + as_[1] + as_[2] + as_[3];
    ss = bs_[0] + bs_[1] + bs_[2] + bs_[3];
    float mu = s * (1.f / 1024.f);
    float var = ss * (1.f / 1024.f) - mu * mu;
    float rs = rsqrtf(var + 1e-6f);
    float4 gv = ((const float4*)gamma)[tid];
    float4 bv = ((const float4*)beta)[tid];
    float4 o4;
    o4.x = xv.x + (hv.x - mu) * rs * gv.x + bv.x;
    o4.y = xv.y + (hv.y - mu) * rs * gv.y + bv.y;
    o4.z = xv.z + (hv.z - mu) * rs * gv.z + bv.z;
    o4.w = xv.w + (hv.w - mu) * rs * gv.w + bv.w;
    ((float4*)(out + (size_t)row * 1024))[tid] = o4;
}

extern "C" void kernel_launch(void* const* d_in, const int* in_sizes, int n_in,
                              void* d_out, int out_size, void* d_ws, size_t ws_size,
                              hipStream_t stream) {
    const float* x = (const float*)d_in[0];
    const float* W1 = (const float*)d_in[1];
    const float* U1 = (const float*)d_in[2];
    const float* b1 = (const float*)d_in[3];
    const float* Wf = (const float*)d_in[4];
    const float* Uf = (const float*)d_in[5];
    const float* bfv = (const float*)d_in[6];
    const float* Wb = (const float*)d_in[7];
    const float* Ub = (const float*)d_in[8];
    const float* bbv = (const float*)d_in[9];
    const float* gamma = (const float*)d_in[10];
    const float* beta = (const float*)d_in[11];
    float* out = (float*)d_out;

    char* ws = (char*)d_ws;
    size_t off = 0;
    auto alloc = [&](size_t bytes) -> void* {
        void* p = ws + off;
        off += (bytes + 255) & ~(size_t)255;
        return p;
    };
    u16* xwA = (u16*)alloc(64ull * 512 * 2048 * 2); // xw1, later xwb (swizzled)
    u16* xwB = (u16*)alloc(64ull * 512 * 2048 * 2); // xwf (swizzled)
    u16* h1  = (u16*)alloc(64ull * 512 * 512 * 2);  // [b*512+t][512]
    u16* xb  = (u16*)alloc(64ull * 512 * 1024 * 2);
    u16* W1t = (u16*)alloc(2048ull * 1024 * 2);
    u16* Wft = (u16*)alloc(2048ull * 512 * 2);
    u16* Wbt = (u16*)alloc(2048ull * 512 * 2);
    u16* U1t = (u16*)alloc(2048ull * 512 * 2);
    u16* Uft = (u16*)alloc(2048ull * 512 * 2);
    u16* Ubt = (u16*)alloc(2048ull * 512 * 2);
    const size_t HB = 2ull * 64 * 512 * 2; // double-buffered h broadcast
    const size_t CT = 4ull * 512 * 4;      // 4 groups x 512 step counters
    char* sync0 = (char*)alloc(3 * (HB + CT));

    u16* hb0 = (u16*)(sync0);
    u32* c0 = (u32*)(sync0 + HB);
    u16* hb1 = (u16*)(sync0 + (HB + CT));
    u32* c1 = (u32*)(sync0 + (HB + CT) + HB);
    u16* hb2 = (u16*)(sync0 + 2 * (HB + CT));
    u32* c2 = (u32*)(sync0 + 2 * (HB + CT) + HB);

    hipMemsetAsync(sync0, 0, 3 * (HB + CT), stream);

    cast_f32_bf16<<<32768, 256, 0, stream>>>(x, xb, 8388608);
    dim3 tb(32, 8);
    transpose_cast<<<dim3(64, 32), tb, 0, stream>>>(W1, W1t, 1024);
    transpose_cast<<<dim3(64, 16), tb, 0, stream>>>(U1, U1t, 512);
    transpose_cast<<<dim3(64, 16), tb, 0, stream>>>(Wf, Wft, 512);
    transpose_cast<<<dim3(64, 16), tb, 0, stream>>>(Uf, Uft, 512);
    transpose_cast<<<dim3(64, 16), tb, 0, stream>>>(Wb, Wbt, 512);
    transpose_cast<<<dim3(64, 16), tb, 0, stream>>>(Ub, Ubt, 512);

    // xw1 = x @ W1 + b1 (swizzled out)
    gemm_bt<<<dim3(16, 256), 256, 0, stream>>>(xb, W1t, b1, xwA, 32768, 2048, 1024);
    // LSTM1 -> h1
    lstm_rec<<<32, 256, 0, stream>>>(xwA, U1t, hb0, c0, h1, nullptr,
                                     xwA, U1t, hb0, c0, nullptr, nullptr, 32);
    // xwf = h1 @ Wf + bf ; xwb = h1 @ Wb + bb
    gemm_bt<<<dim3(16, 256), 256, 0, stream>>>(h1, Wft, bfv, xwB, 32768, 2048, 512);
    gemm_bt<<<dim3(16, 256), 256, 0, stream>>>(h1, Wbt, bbv, xwA, 32768, 2048, 512);
    // fwd (half A) + bwd (half B) LSTMs concurrently
    lstm_rec<<<64, 256, 0, stream>>>(xwB, Uft, hb1, c1, nullptr, out,
                                     xwA, Ubt, hb2, c2, nullptr, out + 512, 32);
    // LayerNorm + residual, in place
    ln_res<<<32768, 256, 0, stream>>>(out, x, gamma, beta);
}